// Round 12
// baseline (1119.291 us; speedup 1.0000x reference)
//
#include <hip/hip_runtime.h>
#include <hip/hip_bf16.h>

#define TT    2048
#define BATCH 64
#define IDIM  128
#define HDIM  256
#define ODIM  512
#define M1    (BATCH * TT)   // 131072 rows

typedef __bf16 bf16x4 __attribute__((ext_vector_type(4)));
typedef __bf16 bf16x8 __attribute__((ext_vector_type(8)));
typedef float  f32x4  __attribute__((ext_vector_type(4)));
typedef _Float16 f16;
typedef _Float16 f16x8 __attribute__((ext_vector_type(8)));

// ---------------------------------------------------------------------------
// GEMM (B-transposed weights): C[m][n] = sum_k A[m][k]*Bw[n][k] + bias[n]
// BM=128 — ~140 us combined, near its BW floor (~107 us), not the bottleneck.
// ---------------------------------------------------------------------------
template<int BM, int NW, int N, int K>
__global__ __launch_bounds__(NW * 64)
void gemm_bt(const float* __restrict__ A, const float* __restrict__ Bw,
             const float* __restrict__ bias, float* __restrict__ C)
{
    constexpr int BN = NW * 64;
    constexpr int BK = 32;
    constexpr int PK = BK + 8;
    constexpr int MF = BM / 16;
    __shared__ __bf16 As[BM][PK];
    __shared__ __bf16 Bs[BN][PK];

    const int tid  = threadIdx.x;
    const int lane = tid & 63;
    const int wave = tid >> 6;
    const int l15  = lane & 15;
    const int l4   = lane >> 4;
    const long mrow = (long)blockIdx.x * BM;

    f32x4 acc[MF][4];
#pragma unroll
    for (int i = 0; i < MF; ++i)
#pragma unroll
        for (int j = 0; j < 4; ++j) acc[i][j] = (f32x4){0.f, 0.f, 0.f, 0.f};

    constexpr int THR   = NW * 64;
    constexpr int A_IT  = (BM * BK) / (THR * 4);
    constexpr int B_IT  = (BN * BK) / (THR * 4);
    static_assert(A_IT * THR * 4 == BM * BK, "A staging mismatch");
    static_assert(B_IT * THR * 4 == BN * BK, "B staging mismatch");

    for (int k0 = 0; k0 < K; k0 += BK) {
#pragma unroll
        for (int it = 0; it < A_IT; ++it) {
            int e = tid * 4 + it * THR * 4;
            int r = e / BK, c = e % BK;
            float4 v = *(const float4*)(A + (mrow + r) * K + (k0 + c));
            bf16x4 p = {(__bf16)v.x, (__bf16)v.y, (__bf16)v.z, (__bf16)v.w};
            *(bf16x4*)&As[r][c] = p;
        }
#pragma unroll
        for (int it = 0; it < B_IT; ++it) {
            int e = tid * 4 + it * THR * 4;
            int r = e / BK, c = e % BK;
            float4 v = *(const float4*)(Bw + (long)r * K + (k0 + c));
            bf16x4 p = {(__bf16)v.x, (__bf16)v.y, (__bf16)v.z, (__bf16)v.w};
            *(bf16x4*)&Bs[r][c] = p;
        }
        __syncthreads();

        const int kk = l4 * 8;
        bf16x8 a[MF], b[4];
#pragma unroll
        for (int mf = 0; mf < MF; ++mf)
            a[mf] = *(const bf16x8*)&As[mf * 16 + l15][kk];
#pragma unroll
        for (int nf = 0; nf < 4; ++nf)
            b[nf] = *(const bf16x8*)&Bs[wave * 64 + nf * 16 + l15][kk];
#pragma unroll
        for (int mf = 0; mf < MF; ++mf)
#pragma unroll
            for (int nf = 0; nf < 4; ++nf)
                acc[mf][nf] = __builtin_amdgcn_mfma_f32_16x16x32_bf16(
                    a[mf], b[nf], acc[mf][nf], 0, 0, 0);
        __syncthreads();
    }

#pragma unroll
    for (int nf = 0; nf < 4; ++nf) {
        const int col = wave * 64 + nf * 16 + l15;
        const float bv = bias[col];
#pragma unroll
        for (int mf = 0; mf < MF; ++mf) {
#pragma unroll
            for (int j = 0; j < 4; ++j) {
                long row = mrow + mf * 16 + l4 * 4 + j;
                C[row * N + col] = acc[mf][nf][j] + bv;
            }
        }
    }
}

// ---------------------------------------------------------------------------
// MFMA scan, 4 waves x 64 rows — R12: tail surgery.
//   * acc-init removed: kt=0 peeled, all 8 chains take ONE shared ZERO f32x4
//     as C-in (saves ~28 v_mov per step).
//   * select-before-add: cndmask-select the owned component from aa and ab
//     separately, then one scalar add (was: 8 f32x4 adds then select).
//   Otherwise identical to R11: A=Whh in regs, broadcast B reads, distance-4
//   xp prefetch, h_all store issued at top of next step, raw s_barrier with
//   lgkmcnt-only drain.
// ---------------------------------------------------------------------------
__global__ __launch_bounds__(256, 1)
void rnn_scan_mfma(const float* __restrict__ xp, const float* __restrict__ h0,
                   const float* __restrict__ Whh, float* __restrict__ h_all)
{
    __shared__ f16 hs[2][HDIM];
    const int tid  = threadIdx.x;
    const int w    = tid >> 6;           // wave 0..3
    const int lane = tid & 63;
    const int q    = lane >> 4;          // 0..3
    const int c    = lane & 15;          // 0..15 (MFMA column)
    const int b    = blockIdx.x;         // batch

    const int mtf = c & 3;               // m-tile this lane finalizes
    const int jj  = c >> 2;              // acc component
    const int r   = 64 * w + 16 * mtf + 4 * q + jj;   // this lane's row

    // ---- static A-fragments: Wf[mt][kt] = Whh[64w+16mt+c][32kt+8q+0..7]
    f16x8 Wf[4][8];
#pragma unroll
    for (int mt = 0; mt < 4; ++mt) {
        const float* wrp = Whh + (long)(64 * w + 16 * mt + c) * HDIM + 8 * q;
#pragma unroll
        for (int kt = 0; kt < 8; ++kt) {
            f32x4 u0 = *(const f32x4*)(wrp + 32 * kt);
            f32x4 u1 = *(const f32x4*)(wrp + 32 * kt + 4);
            Wf[mt][kt] = (f16x8){(f16)u0[0], (f16)u0[1], (f16)u0[2], (f16)u0[3],
                                 (f16)u1[0], (f16)u1[1], (f16)u1[2], (f16)u1[3]};
        }
    }

    // ---- init h buffer 0 (f16): 256 threads == HDIM
    hs[0][tid] = (f16)h0[(long)b * HDIM + tid];
    float hold = h0[(long)b * HDIM + r];
    __syncthreads();

    const float* xpb = xp + (long)b * TT * HDIM + r;   // walks t+4 reads
    // store pointer starts one row BEHIND: first store (h0 value) lands at
    // h_all - HDIM = last y-row (dead scratch, overwritten later by K3).
    float* hab = h_all + (long)b * TT * HDIM + r - HDIM;

    float xq0 = xpb[0 * HDIM];
    float xq1 = xpb[1 * HDIM];
    float xq2 = xpb[2 * HDIM];
    float xq3 = xpb[3 * HDIM];
    xpb += 4 * HDIM;
    float hn_prev = hold;

    const f32x4 ZERO = (f32x4){0.f, 0.f, 0.f, 0.f};

    // One scan step. Over-reads xp by <=4 rows at the tail (scratch, unused).
#define SCAN_STEP(CUR, NXT, XQ)                                                 \
    {                                                                           \
        const f16* hb = hs[CUR];                                                \
        f16x8 Bf[8];                                                            \
        _Pragma("unroll")                                                       \
        for (int kt = 0; kt < 8; ++kt)                                          \
            Bf[kt] = *(const f16x8*)(hb + 32 * kt + 8 * q);                     \
        hab[0] = hn_prev;               /* prev step's h_all, under ds_reads */ \
        hab += HDIM;                                                            \
        float xcur = XQ;                                                        \
        XQ = xpb[0];                    /* prefetch t+4, distance-4 slot */     \
        xpb += HDIM;                                                            \
        f32x4 aa[4], ab[4];                                                     \
        /* kt=0/4 peeled: C-in = shared ZERO (no 32-mov acc init) */            \
        _Pragma("unroll")                                                       \
        for (int mt = 0; mt < 4; ++mt) {                                        \
            aa[mt] = __builtin_amdgcn_mfma_f32_16x16x32_f16(                    \
                Wf[mt][0], Bf[0], ZERO, 0, 0, 0);                               \
            ab[mt] = __builtin_amdgcn_mfma_f32_16x16x32_f16(                    \
                Wf[mt][4], Bf[4], ZERO, 0, 0, 0);                               \
        }                                                                       \
        _Pragma("unroll")                                                       \
        for (int kt = 1; kt < 4; ++kt) {                                        \
            _Pragma("unroll")                                                   \
            for (int mt = 0; mt < 4; ++mt) {                                    \
                aa[mt] = __builtin_amdgcn_mfma_f32_16x16x32_f16(                \
                    Wf[mt][kt],     Bf[kt],     aa[mt], 0, 0, 0);               \
                ab[mt] = __builtin_amdgcn_mfma_f32_16x16x32_f16(                \
                    Wf[mt][kt + 4], Bf[kt + 4], ab[mt], 0, 0, 0);               \
            }                                                                   \
        }                                                                       \
        /* select-before-add: pick owned component from aa and ab, then add */  \
        f32x4 va0 = (c & 1) ? aa[1] : aa[0];                                    \
        f32x4 va1 = (c & 1) ? aa[3] : aa[2];                                    \
        f32x4 vam = (c & 2) ? va1 : va0;                                        \
        float sax = (jj & 2) ? vam[2] : vam[0];                                 \
        float say = (jj & 2) ? vam[3] : vam[1];                                 \
        float sa  = (jj & 1) ? say : sax;                                       \
        f32x4 vb0 = (c & 1) ? ab[1] : ab[0];                                    \
        f32x4 vb1 = (c & 1) ? ab[3] : ab[2];                                    \
        f32x4 vbm = (c & 2) ? vb1 : vb0;                                        \
        float sbx = (jj & 2) ? vbm[2] : vbm[0];                                 \
        float sby = (jj & 2) ? vbm[3] : vbm[1];                                 \
        float sb  = (jj & 1) ? sby : sbx;                                       \
        float pre = (sa + sb) + xcur;                                           \
        float e   = exp2f(pre * 2.885390082f);   /* e^{2*pre} */                \
        float rc  = __builtin_amdgcn_rcpf(1.f + e);                             \
        float hn  = fmaf(0.9f, hold, 0.1f) - 0.2f * rc;                         \
        hold = hn;                                                              \
        hs[NXT][r] = (f16)hn;                                                   \
        hn_prev = hn;                                                           \
        __builtin_amdgcn_sched_barrier(0);                                      \
        asm volatile("s_waitcnt lgkmcnt(0)" ::: "memory");                      \
        __builtin_amdgcn_s_barrier();                                           \
        __builtin_amdgcn_sched_barrier(0);                                      \
    }

    for (int t = 0; t < TT; t += 4) {
        SCAN_STEP(0, 1, xq0);
        SCAN_STEP(1, 0, xq1);
        SCAN_STEP(0, 1, xq2);
        SCAN_STEP(1, 0, xq3);
    }
#undef SCAN_STEP
    hab[0] = hn_prev;   // final h_all[t = TT-1]
}

// ---------------------------------------------------------------------------
extern "C" void kernel_launch(void* const* d_in, const int* in_sizes, int n_in,
                              void* d_out, int out_size, void* d_ws, size_t ws_size,
                              hipStream_t stream)
{
    const float* x   = (const float*)d_in[0];
    const float* h0  = (const float*)d_in[1];
    const float* Wxh = (const float*)d_in[2];
    const float* bxh = (const float*)d_in[3];
    const float* Whh = (const float*)d_in[4];
    const float* Why = (const float*)d_in[5];
    const float* bhy = (const float*)d_in[6];

    float* y     = (float*)d_out;                 // (M1, 512)
    float* h_all = y + (long)M1 * ODIM;           // (M1, 256)
    float* xp    = y;   // scratch: xp fits in y region; dead before K3

    gemm_bt<128, 4, HDIM, IDIM><<<M1 / 128, 4 * 64, 0, stream>>>(x, Wxh, bxh, xp);
    rnn_scan_mfma<<<BATCH, 256, 0, stream>>>(xp, h0, Whh, h_all);
    gemm_bt<128, 8, ODIM, HDIM><<<M1 / 128, 8 * 64, 0, stream>>>(h_all, Why, bhy, y);
}